// Round 1
// baseline (1262.091 us; speedup 1.0000x reference)
//
#include <hip/hip_runtime.h>
#include <math.h>

// Problem constants (from reference): B=128, MAXLEN=20, E=H=512, V=32000
#define NB 128
#define NT 20
#define NE 512
#define NH 512
#define NV 32000
#define NG 2048   // 4*H
#define NK 512    // E == H

union F4 { float4 v; float f[4]; };

__device__ __forceinline__ float sigmoidf_(float x) {
    return 1.0f / (1.0f + expf(-x));
}

// ---------------------------------------------------------------------------
// prep: bias = b_ih + b_hh; aptr1[m] = source row for x[t][b]; aptr3[r] =
// source row in Hs for packed output row r (pack_padded order).
// ---------------------------------------------------------------------------
__global__ __launch_bounds__(256) void prep_kernel(
    const float* __restrict__ features, const int* __restrict__ captions,
    const int* __restrict__ lengths, const float* __restrict__ embed_w,
    const float* __restrict__ b_ih, const float* __restrict__ b_hh,
    float* __restrict__ bias, const float** __restrict__ aptr1,
    const float** __restrict__ aptr3, const float* __restrict__ Hs,
    int mpad3)
{
    const int tid = threadIdx.x;
    for (int j = tid; j < NG; j += 256) bias[j] = b_ih[j] + b_hh[j];
    for (int m = tid; m < NT * NB; m += 256) {
        int t = m >> 7, b = m & 127;
        aptr1[m] = (t == 0) ? (features + (size_t)b * NE)
                            : (embed_w + (size_t)captions[b * NT + t - 1] * NE);
    }
    // pack indices: for t in 0..T-1, rows b with lengths[b] > t, in b order
    __shared__ unsigned long long s_mask[4];
    __shared__ int s_off;
    if (tid == 0) s_off = 0;
    const int len  = (tid < NB) ? lengths[tid] : 0;
    const int lane = tid & 63, wv = tid >> 6;
    __syncthreads();
    for (int t = 0; t < NT; ++t) {
        const bool flag = (len > t);
        unsigned long long bm = __ballot(flag ? 1 : 0);
        if (lane == 0) s_mask[wv] = bm;
        __syncthreads();
        int pos = s_off;
        for (int w = 0; w < wv; ++w) pos += __popcll(s_mask[w]);
        pos += __popcll(bm & ((1ull << lane) - 1ull));
        if (flag) aptr3[pos] = Hs + ((size_t)(t * NB + tid)) * NH;
        __syncthreads();
        if (tid == 0) {
            int tot = 0;
            for (int w = 0; w < 4; ++w) tot += __popcll(s_mask[w]);
            s_off += tot;
        }
        __syncthreads();
    }
    for (int m = s_off + tid; m < mpad3; m += 256) aptr3[m] = Hs;  // pad rows
}

// ---------------------------------------------------------------------------
// Generic fp32 GEMM, gathered A rows: C[m][n] = sum_k aptr[m][k]*Bmat[n][k]
// + bias[n].  Tile 128x128, K=512, KB=16, 256 threads, 8x8 per thread.
// ---------------------------------------------------------------------------
__global__ __launch_bounds__(256) void gemm128_kernel(
    const float* const* __restrict__ aptr, const float* __restrict__ Bmat,
    const float* __restrict__ bias, float* __restrict__ C,
    int N, int Mlimit)
{
    __shared__ float At[16][132];
    __shared__ float Bt[16][132];
    const int tid = threadIdx.x;
    const int m0 = blockIdx.x << 7, n0 = blockIdx.y << 7;
    const int tx = tid & 15, ty = tid >> 4;
    const int lr0 = tid >> 2;            // load row 0..63
    const int lr1 = lr0 + 64;            // load row 64..127
    const int lc0 = (tid & 3) << 2;      // k sub-offset {0,4,8,12}

    const float* arow0 = aptr[m0 + lr0];
    const float* arow1 = aptr[m0 + lr1];
    const float* brow0 = Bmat + (size_t)(n0 + lr0) * NK;
    const float* brow1 = Bmat + (size_t)(n0 + lr1) * NK;

    float acc[8][8];
#pragma unroll
    for (int i = 0; i < 8; ++i)
#pragma unroll
        for (int j = 0; j < 8; ++j) acc[i][j] = 0.0f;

    for (int k0 = 0; k0 < NK; k0 += 16) {
        F4 a0, a1, b0, b1;
        a0.v = *(const float4*)(arow0 + k0 + lc0);
        a1.v = *(const float4*)(arow1 + k0 + lc0);
        b0.v = *(const float4*)(brow0 + k0 + lc0);
        b1.v = *(const float4*)(brow1 + k0 + lc0);
        __syncthreads();  // protect previous iteration's reads
#pragma unroll
        for (int i = 0; i < 4; ++i) {
            At[lc0 + i][lr0] = a0.f[i];
            At[lc0 + i][lr1] = a1.f[i];
            Bt[lc0 + i][lr0] = b0.f[i];
            Bt[lc0 + i][lr1] = b1.f[i];
        }
        __syncthreads();
#pragma unroll
        for (int kk = 0; kk < 16; ++kk) {
            F4 va0, va1, vb0, vb1;
            va0.v = *(const float4*)&At[kk][ty << 2];
            va1.v = *(const float4*)&At[kk][64 + (ty << 2)];
            vb0.v = *(const float4*)&Bt[kk][tx << 2];
            vb1.v = *(const float4*)&Bt[kk][64 + (tx << 2)];
            float a[8], b[8];
#pragma unroll
            for (int i = 0; i < 4; ++i) { a[i] = va0.f[i]; a[i + 4] = va1.f[i]; }
#pragma unroll
            for (int j = 0; j < 4; ++j) { b[j] = vb0.f[j]; b[j + 4] = vb1.f[j]; }
#pragma unroll
            for (int i = 0; i < 8; ++i)
#pragma unroll
                for (int j = 0; j < 8; ++j) acc[i][j] = fmaf(a[i], b[j], acc[i][j]);
        }
    }

    F4 bs0, bs1;
    bs0.v = *(const float4*)(bias + n0 + (tx << 2));
    bs1.v = *(const float4*)(bias + n0 + 64 + (tx << 2));
#pragma unroll
    for (int i = 0; i < 8; ++i) {
        const int r = m0 + ((i < 4) ? ((ty << 2) + i) : (64 + (ty << 2) + i - 4));
        if (r < Mlimit) {
            F4 v0, v1;
#pragma unroll
            for (int j = 0; j < 4; ++j) {
                v0.f[j] = acc[i][j] + bs0.f[j];
                v1.f[j] = acc[i][j + 4] + bs1.f[j];
            }
            *(float4*)(C + (size_t)r * N + n0 + (tx << 2))      = v0.v;
            *(float4*)(C + (size_t)r * N + n0 + 64 + (tx << 2)) = v1.v;
        }
    }
}

// ---------------------------------------------------------------------------
// Recurrent partial GEMM: pbuf[kz][b][g*512+n] = sum_{k in kz-range}
// h[b][k] * w_hh[g*512+n][k].  Grid (4 btiles, 16 ntiles, 4 ksplit).
// Per thread: 2 b x 2 n x 4 gates.
// ---------------------------------------------------------------------------
__global__ __launch_bounds__(256) void gemmr_kernel(
    const float* __restrict__ hsrc, const float* __restrict__ w_hh,
    float* __restrict__ pbuf)
{
    __shared__ float Ht[32][34];
    __shared__ float Wt[32][32][4];
    const int tid = threadIdx.x;
    const int b0 = blockIdx.x << 5;
    const int n0 = blockIdx.y << 5;
    const int kz = blockIdx.z;
    const int tx = tid & 15, ty = tid >> 4;

    const int hlr = tid >> 3;            // 0..31
    const int hlc = (tid & 7) << 2;      // {0..28}
    const int wnl = tid >> 3;            // 0..31
    const int wc  = (tid & 7) << 2;

    float acc[2][2][4];
#pragma unroll
    for (int bi = 0; bi < 2; ++bi)
#pragma unroll
        for (int ni = 0; ni < 2; ++ni)
#pragma unroll
            for (int g = 0; g < 4; ++g) acc[bi][ni][g] = 0.0f;

    const int kbeg = kz << 7;
    for (int k0 = kbeg; k0 < kbeg + 128; k0 += 32) {
        F4 hv;
        hv.v = *(const float4*)(hsrc + (size_t)(b0 + hlr) * NH + k0 + hlc);
        F4 wv[4];
#pragma unroll
        for (int g = 0; g < 4; ++g)
            wv[g].v = *(const float4*)(w_hh + (size_t)(g * NH + n0 + wnl) * NK + k0 + wc);
        __syncthreads();
#pragma unroll
        for (int i = 0; i < 4; ++i) {
            Ht[hlc + i][hlr] = hv.f[i];
#pragma unroll
            for (int g = 0; g < 4; ++g) Wt[wc + i][wnl][g] = wv[g].f[i];
        }
        __syncthreads();
#pragma unroll
        for (int kk = 0; kk < 32; ++kk) {
            float2 h2 = *(const float2*)&Ht[kk][ty << 1];
            F4 w0, w1;
            w0.v = *(const float4*)&Wt[kk][tx][0];
            w1.v = *(const float4*)&Wt[kk][tx + 16][0];
#pragma unroll
            for (int g = 0; g < 4; ++g) {
                acc[0][0][g] = fmaf(h2.x, w0.f[g], acc[0][0][g]);
                acc[0][1][g] = fmaf(h2.x, w1.f[g], acc[0][1][g]);
                acc[1][0][g] = fmaf(h2.y, w0.f[g], acc[1][0][g]);
                acc[1][1][g] = fmaf(h2.y, w1.f[g], acc[1][1][g]);
            }
        }
        __syncthreads();
    }
#pragma unroll
    for (int bi = 0; bi < 2; ++bi) {
        const int b = b0 + (ty << 1) + bi;
#pragma unroll
        for (int g = 0; g < 4; ++g) {
            float* p = pbuf + (size_t)(kz * NB + b) * NG + g * NH + n0 + tx;
            p[0]  = acc[bi][0][g];
            p[16] = acc[bi][1][g];
        }
    }
}

// ---------------------------------------------------------------------------
// cell: gates = Xgate[t] + sum_ks pbuf[ks]; LSTM pointwise; writes c_new and
// h_new (h_new also into Hs[t]).
// ---------------------------------------------------------------------------
__global__ __launch_bounds__(256) void cell_kernel(
    const float* __restrict__ Xg, const float* __restrict__ pbuf,
    const float* __restrict__ cin, float* __restrict__ cout,
    float* __restrict__ hout)
{
    const int tid = blockIdx.x * 256 + threadIdx.x;   // 0..16383
    const int b = tid >> 7, n4 = tid & 127;
    const int n = n4 << 2;

    F4 gv[4];
#pragma unroll
    for (int g = 0; g < 4; ++g) {
        const size_t off = (size_t)b * NG + g * NH + n;
        F4 x; x.v = *(const float4*)(Xg + off);
#pragma unroll
        for (int ks = 0; ks < 4; ++ks) {
            F4 p; p.v = *(const float4*)(pbuf + (size_t)ks * NB * NG + off);
#pragma unroll
            for (int e = 0; e < 4; ++e) x.f[e] += p.f[e];
        }
        gv[g] = x;
    }
    F4 c; c.v = *(const float4*)(cin + (size_t)b * NH + n);
    F4 cn, hn;
#pragma unroll
    for (int e = 0; e < 4; ++e) {
        const float ig = sigmoidf_(gv[0].f[e]);
        const float fg = sigmoidf_(gv[1].f[e]);
        const float gg = tanhf(gv[2].f[e]);
        const float og = sigmoidf_(gv[3].f[e]);
        const float cv = fg * c.f[e] + ig * gg;
        cn.f[e] = cv;
        hn.f[e] = og * tanhf(cv);
    }
    *(float4*)(cout + (size_t)b * NH + n) = cn.v;
    *(float4*)(hout + (size_t)b * NH + n) = hn.v;
}

// ---------------------------------------------------------------------------
extern "C" void kernel_launch(void* const* d_in, const int* in_sizes, int n_in,
                              void* d_out, int out_size, void* d_ws, size_t ws_size,
                              hipStream_t stream) {
    const float* features = (const float*)d_in[0];
    const int*   captions = (const int*)d_in[1];
    const int*   lengths  = (const int*)d_in[2];
    const float* h0       = (const float*)d_in[3];
    const float* c0       = (const float*)d_in[4];
    const float* embed_w  = (const float*)d_in[5];
    const float* w_ih     = (const float*)d_in[6];
    const float* w_hh     = (const float*)d_in[7];
    const float* b_ih     = (const float*)d_in[8];
    const float* b_hh     = (const float*)d_in[9];
    const float* lin_w    = (const float*)d_in[10];
    const float* lin_b    = (const float*)d_in[11];
    float* out = (float*)d_out;

    const int M3    = out_size / NV;          // total packed rows (1600)
    const int mt3   = (M3 + 127) >> 7;        // projection M tiles
    const int mpad3 = mt3 << 7;

    char* w = (char*)d_ws;
    float* Xgate = (float*)w; w += sizeof(float) * (size_t)NT * NB * NG;   // 21 MB
    float* Hs    = (float*)w; w += sizeof(float) * (size_t)NT * NB * NH;   // 5.2 MB
    float* cbuf  = (float*)w; w += sizeof(float) * (size_t)2 * NB * NH;    // 0.5 MB
    float* pbuf  = (float*)w; w += sizeof(float) * (size_t)4 * NB * NG;    // 4.2 MB
    float* bias  = (float*)w; w += sizeof(float) * NG;
    const float** aptr1 = (const float**)w; w += sizeof(float*) * NT * NB;
    const float** aptr3 = (const float**)w; w += sizeof(float*) * mpad3;

    prep_kernel<<<1, 256, 0, stream>>>(features, captions, lengths, embed_w,
                                       b_ih, b_hh, bias, aptr1, aptr3, Hs, mpad3);

    // Xgate[t*B+b][:] = x_t[b] @ w_ih^T + (b_ih + b_hh)
    gemm128_kernel<<<dim3(NT * NB / 128, NG / 128), 256, 0, stream>>>(
        aptr1, w_ih, bias, Xgate, NG, NT * NB);

    static float zero_bias_dummy;  // unused
    (void)zero_bias_dummy;

    for (int t = 0; t < NT; ++t) {
        const float* hsrc = t ? (Hs + (size_t)(t - 1) * NB * NH) : h0;
        const float* csrc = t ? (cbuf + (size_t)((t - 1) & 1) * NB * NH) : c0;
        float* cdst = cbuf + (size_t)(t & 1) * NB * NH;
        gemmr_kernel<<<dim3(4, 16, 4), 256, 0, stream>>>(hsrc, w_hh, pbuf);
        cell_kernel<<<64, 256, 0, stream>>>(Xgate + (size_t)t * NB * NG, pbuf,
                                            csrc, cdst,
                                            Hs + (size_t)t * NB * NH);
    }

    // packed projection: out[r][:] = Hs[idx[r]][:] @ lin_w^T + lin_b
    gemm128_kernel<<<dim3(mt3, NV / 128), 256, 0, stream>>>(
        aptr3, lin_w, lin_b, out, NV, M3);
}